// Round 12
// baseline (111.479 us; speedup 1.0000x reference)
//
#include <hip/hip_runtime.h>

// SSIM loss, wave-autonomous + register ring buffer. B=32, H=W=512, win=11.
// R12 = R10 exactly (920 blocks, 5 strips x 23 bands x 22 rows, guard-free,
// DPP-only wave_shl hwin) with ONE change: vertical-moment + SSIM arithmetic
// packed as float2 (v_pk_add_f32 / v_pk_fma_f32) -- ~23 fewer instrs/iter.
// Per-component op sequence identical to R10 => absmax 0 expected.

#define WW 512
#define OH 502
#define BANDR 22
#define NBANDS 23
#define INV_N (1.0f / 8064128.0f)   // 32*502*502

// lane l receives lane l+1's value; bound_ctrl=1 (OOB -> 0).
__device__ __forceinline__ float shl1(float x) {
    return __int_as_float(__builtin_amdgcn_update_dpp(
        0, __float_as_int(x), 0x130, 0xf, 0xf, true));
}

// 11-tap horizontal window sums for this lane's two columns (2l, 2l+1).
// A = pairs l..l+5 (cols 2l..2l+11); u = col 2l+11.
// W0 = A - u = cols 2l..2l+10; W1 = A - v0 = cols 2l+1..2l+11.  (R8-verified)
__device__ __forceinline__ float2 hwin(float v0, float v1) {
    float e = v0 + v1;
    float t = shl1(e);  float A = e + t;
    t = shl1(t);  A += t;
    t = shl1(t);  A += t;
    t = shl1(t);  A += t;
    t = shl1(t);  A += t;
    float u = shl1(v1);
    u = shl1(u); u = shl1(u); u = shl1(u); u = shl1(u);  // v1[l+5] = col 2l+11
    return make_float2(A - u, A - v0);
}

// float2 packed-math helpers (target v_pk_add_f32 / v_pk_fma_f32)
__device__ __forceinline__ float2 f2add(float2 a, float2 b){ return make_float2(a.x+b.x, a.y+b.y); }
__device__ __forceinline__ float2 f2sub(float2 a, float2 b){ return make_float2(a.x-b.x, a.y-b.y); }
__device__ __forceinline__ float2 f2mul(float2 a, float2 b){ return make_float2(a.x*b.x, a.y*b.y); }
__device__ __forceinline__ float2 f2fma(float2 a, float2 b, float2 c){
    return make_float2(fmaf(a.x,b.x,c.x), fmaf(a.y,b.y,c.y)); }
__device__ __forceinline__ float2 f2fms(float2 a, float2 b, float2 c){   // a*b - c
    return make_float2(fmaf(a.x,b.x,-c.x), fmaf(a.y,b.y,-c.y)); }
__device__ __forceinline__ float2 f2nfma(float2 a, float2 b, float2 c){  // c - a*b
    return make_float2(fmaf(-a.x,b.x,c.x), fmaf(-a.y,b.y,c.y)); }

// SSIM for the lane's two output columns (packed across the .x/.y pair).
__device__ __forceinline__ float ssim2(float2 w0, float2 w1, float2 w2, float2 w3,
                                       bool valid) {
    const float NP = 121.f, cn = 121.f/120.f;
    const float2 C1n = make_float2(1.21e-2f*121.f, 1.21e-2f*121.f);   // 1e-4*121^2
    const float2 C2n = make_float2(1.089e-1f*121.f, 1.089e-1f*121.f); // 9e-4*121^2
    const float2 NP2 = make_float2(NP, NP);
    float2 m1 = f2mul(w0, w1);
    float2 q1 = f2fma(w0, w0, f2mul(w1, w1));
    float2 A1 = f2fma(make_float2(2.f,2.f), m1, C1n);
    float2 B1 = f2add(q1, C1n);
    float2 A2 = f2fma(make_float2(2.f*cn,2.f*cn), f2fms(NP2, w3, m1), C2n);
    float2 B2 = f2fma(make_float2(cn,cn), f2fms(NP2, w2, q1), C2n);
    float2 num = f2mul(A1, A2), den = f2mul(B1, B2);
    float r = fmaf(num.x, __builtin_amdgcn_rcpf(den.x),
                   num.y * __builtin_amdgcn_rcpf(den.y));
    return valid ? r : 0.f;
}

__global__ __launch_bounds__(256)
void ssim_main(const float* __restrict__ Pg, const float* __restrict__ Tg,
               float* __restrict__ outp) {
    const int tid  = threadIdx.x;
    const int lane = tid & 63;
    const int wv   = tid >> 6;
    const int Wid  = blockIdx.x * 4 + wv;      // 0..3679
    const int img   = Wid / 115;               // 5 strips * 23 bands
    const int rem   = Wid - img * 115;
    const int strip = rem / NBANDS;
    const int band  = rem - strip * NBANDS;

    const int col0 = (strip == 4) ? 472 : strip * 118;
    const int outw = (strip == 4) ? 30 : 118;
    const int y0   = band * BANDR;             // band 22: 484 (18 real rows)

    const int cload = min(col0 + 2 * lane, 510);
    const bool ok   = lane < (outw >> 1);

    const float* Pb = Pg + img * (WW * WW);
    const float* Tb = Tg + img * (WW * WW);

    float2 prr[11], trr[11];
    float2 sp = make_float2(0,0), st = make_float2(0,0);
    float2 sq = make_float2(0,0), sx = make_float2(0,0);

    // ---- prime: input rows y0..y0+9 into ring slots 0..9 ----
    #pragma unroll
    for (int r = 0; r < 10; ++r) {
        float2 p = *(const float2*)(Pb + (y0 + r) * WW + cload);
        float2 t = *(const float2*)(Tb + (y0 + r) * WW + cload);
        prr[r] = p; trr[r] = t;
        sp = f2add(sp, p); st = f2add(st, t);
        sq = f2fma(p, p, sq); sq = f2fma(t, t, sq);
        sx = f2fma(p, t, sx);
    }
    // depth-3 prefetch pipeline: rows y0+10 .. y0+12 (always valid addresses)
    float2 Pn0 = *(const float2*)(Pb + (y0 + 10) * WW + cload);
    float2 Tn0 = *(const float2*)(Tb + (y0 + 10) * WW + cload);
    float2 Pn1 = *(const float2*)(Pb + (y0 + 11) * WW + cload);
    float2 Tn1 = *(const float2*)(Tb + (y0 + 11) * WW + cload);
    float2 Pn2 = *(const float2*)(Pb + min(y0 + 12, 511) * WW + cload);
    float2 Tn2 = *(const float2*)(Tb + min(y0 + 12, 511) * WW + cload);

    float acc = 0.f;

    for (int blk = 0; blk < 2; ++blk) {          // 2 x 11 = 22 rows, no guards
        #pragma unroll
        for (int j = 0; j < 11; ++j) {
            const int sn = (10 + j) % 11;        // static ring slot
            const int y  = y0 + 11 * blk + j;    // output row this iter makes
            // consume prefetched row (loaded 3 iterations ago)
            float2 Pc = Pn0, Tc = Tn0;
            // rotate pipeline (straight-line: renamed, no real moves)
            Pn0 = Pn1; Tn0 = Tn1;
            Pn1 = Pn2; Tn1 = Tn2;
            int nr = min(y + 13, 511);
            Pn2 = *(const float2*)(Pb + nr * WW + cload);
            Tn2 = *(const float2*)(Tb + nr * WW + cload);
            // vertical: add new row (packed)
            prr[sn] = Pc; trr[sn] = Tc;
            sp = f2add(sp, Pc); st = f2add(st, Tc);
            sq = f2fma(Pc, Pc, sq); sq = f2fma(Tc, Tc, sq);
            sx = f2fma(Pc, Tc, sx);
            // horizontal windows + SSIM (pure DPP)
            float2 w0 = hwin(sp.x, sp.y);
            float2 w1 = hwin(st.x, st.y);
            float2 w2 = hwin(sq.x, sq.y);
            float2 w3 = hwin(sx.x, sx.y);
            acc += ssim2(w0, w1, w2, w3, ok && (y < OH));
            // vertical: subtract oldest row (ring slot j, packed)
            float2 po = prr[j], to = trr[j];
            sp = f2sub(sp, po); st = f2sub(st, to);
            sq = f2nfma(po, po, sq); sq = f2nfma(to, to, sq);
            sx = f2nfma(po, to, sx);
        }
    }

    // ---- reduce: wave -> block -> one atomicAdd ----
    #pragma unroll
    for (int off = 32; off > 0; off >>= 1) acc += __shfl_down(acc, off);
    __shared__ float wred[4];
    if (lane == 0) wred[wv] = acc;
    __syncthreads();
    if (tid == 0) {
        float s = wred[0] + wred[1] + wred[2] + wred[3];
        float contrib = -s * INV_N;
        if (blockIdx.x == 0) contrib += 1.0f;
        atomicAdd(outp, contrib);
    }
}

extern "C" void kernel_launch(void* const* d_in, const int* in_sizes, int n_in,
                              void* d_out, int out_size, void* d_ws, size_t ws_size,
                              hipStream_t stream) {
    const float* pred = (const float*)d_in[0];
    const float* targ = (const float*)d_in[1];
    float* out = (float*)d_out;

    hipMemsetAsync(out, 0, sizeof(float), stream);
    ssim_main<<<dim3(920), dim3(256), 0, stream>>>(pred, targ, out);
}